// Round 1
// baseline (1765.199 us; speedup 1.0000x reference)
//
#include <hip/hip_runtime.h>
#include <math.h>

// SubsetOperator: relaxed top-K (K=16) Gumbel-softmax, rows of N=4096.
// Exp-domain recurrence (verified in prior rounds): e *= max(1-p, EPS)
// replaces s += log(max(1-p,EPS)); softmax(s).
//
// R3: occupancy fix. One 256-thread block (4 waves) per ROW, 16 elements
// per lane -> live state e[16]+kh[16] = 32 VGPRs (was 128 with 1 wave/row).
// __launch_bounds__(256,8) forces the <=64-VGPR tier -> 8 waves/SIMD
// resident (was ~3). Cross-wave reduce: intra-wave shfl butterfly, then a
// double-buffered 2x4-float LDS slot with ONE __syncthreads per round
// (parity alternation removes the WAR hazard). Next round's sum is fused
// into the update loop (no separate tree pass over the register file).

#define ROW_N 4096
#define TPB   256
#define C4    4   // float4 chunks per thread: 16 elements/lane

typedef float f4 __attribute__((ext_vector_type(4)));

__device__ __forceinline__ float wave_sum(float v) {
#pragma unroll
    for (int off = 32; off > 0; off >>= 1)
        v += __shfl_xor(v, off, 64);
    return v;
}

__device__ __forceinline__ float wave_max(float v) {
#pragma unroll
    for (int off = 32; off > 0; off >>= 1)
        v = fmaxf(v, __shfl_xor(v, off, 64));
    return v;
}

__global__ __launch_bounds__(TPB, 8) void subset_topk_kernel(
    const float* __restrict__ scores,
    const float* __restrict__ gnoise,
    float* __restrict__ out)
{
    constexpr float EPS = 1.17549435e-38f;  // np.finfo(float32).tiny

    // Double-buffered cross-wave reduction slots. Phase ph writes buffer
    // ph&1; reads of buffer B in phase ph complete before the barrier of
    // phase ph+1, which precedes the next write to B (phase ph+2). So one
    // barrier per phase suffices. Max-phase = ph 0, round k = ph k+1.
    __shared__ float red[2][4] __attribute__((aligned(16)));

    const int tid  = threadIdx.x;
    const int wave = tid >> 6;
    const int lane = tid & 63;

    const size_t base = (size_t)blockIdx.x * ROW_N;
    const f4* s4 = (const f4*)(scores + base);
    const f4* g4 = (const f4*)(gnoise + base);
    f4*       o4 = (f4*)(out + base);

    // ---- load s0 = scores + g (coalesced float4), track running max ----
    f4 e[C4];
    f4 vmax;
#pragma unroll
    for (int j = 0; j < C4; ++j) {
        f4 a = s4[j * TPB + tid];
        f4 b = g4[j * TPB + tid];
        e[j] = a + b;
        vmax = (j == 0) ? e[j] : __builtin_elementwise_max(vmax, e[j]);
    }
    float m = fmaxf(fmaxf(vmax.x, vmax.y), fmaxf(vmax.z, vmax.w));
    m = wave_max(m);
    if (lane == 0) red[0][wave] = m;       // phase 0 -> buffer 0
    __syncthreads();
    {
        f4 r = *(const f4*)&red[0][0];     // broadcast ds_read_b128
        m = fmaxf(fmaxf(r.x, r.y), fmaxf(r.z, r.w));
    }

    // ---- e = exp(s0 - m), kh = 0, per-lane partial sum ----
    f4 kh[C4];
    f4 acc = {0.f, 0.f, 0.f, 0.f};
#pragma unroll
    for (int j = 0; j < C4; ++j) {
        f4 t = e[j] - m;
        e[j].x = __expf(t.x);
        e[j].y = __expf(t.y);
        e[j].z = __expf(t.z);
        e[j].w = __expf(t.w);
        kh[j] = (f4){0.f, 0.f, 0.f, 0.f};
        acc += e[j];
    }
    float part = (acc.x + acc.y) + (acc.z + acc.w);

    const f4 eps4 = {EPS, EPS, EPS, EPS};

    // ---- 16 rounds: cross-wave sum -> p -> accumulate -> mask ----
#pragma unroll
    for (int k = 0; k < 16; ++k) {
        float ws = wave_sum(part);
        const int buf = (k + 1) & 1;       // phase k+1 -> buffer (k+1)&1
        if (lane == 0) red[buf][wave] = ws;
        __syncthreads();
        f4 r = *(const f4*)&red[buf][0];
        float S = (r.x + r.y) + (r.z + r.w);
        const float invS = __builtin_amdgcn_rcpf(S);

        f4 nacc = {0.f, 0.f, 0.f, 0.f};
#pragma unroll
        for (int j = 0; j < C4; ++j) {
            f4 t = e[j] * invS;            // p
            kh[j] += t;
            f4 q = __builtin_elementwise_max(1.0f - t, eps4);
            e[j] *= q;
            nacc += e[j];                  // fused: next round's sum
        }
        part = (nacc.x + nacc.y) + (nacc.z + nacc.w);
    }

    // ---- store khot (coalesced float4) ----
#pragma unroll
    for (int j = 0; j < C4; ++j)
        o4[j * TPB + tid] = kh[j];
}

extern "C" void kernel_launch(void* const* d_in, const int* in_sizes, int n_in,
                              void* d_out, int out_size, void* d_ws, size_t ws_size,
                              hipStream_t stream) {
    const float* scores = (const float*)d_in[0];
    const float* gnoise = (const float*)d_in[1];
    float* out = (float*)d_out;

    const int rows = in_sizes[0] / ROW_N;   // 8192 rows, one block each
    subset_topk_kernel<<<rows, TPB, 0, stream>>>(scores, gnoise, out);
}

// Round 2
// 1074.296 us; speedup vs baseline: 1.6431x; 1.6431x over previous
//
#include <hip/hip_runtime.h>
#include <math.h>

// SubsetOperator: relaxed top-K (K=16) Gumbel-softmax, rows of N=4096.
// Exp-domain recurrence (verified): e *= max(1-p, EPS) replaces
// s += log(max(1-p,EPS)); softmax(s).
//
// R4: same structure as R3 (one 256-thread block / row, 16 elems/lane,
// double-buffered 4-float LDS reduce, ONE barrier per round) but
// __launch_bounds__(256,4): R3's (256,8) capped the unified reg file at
// 64 and spilled e[]/kh[] to scratch -> 16x HBM traffic, 1580us.
// (256,4) caps at 128 regs: state (32 floats) + temps fit with zero
// spill, and still >=4 waves/SIMD vs R0's ~3 (R0 parked 128 floats of
// state in VGPR+AGPR -> 84+64 regs -> 3 waves/SIMD, VALUBusy 56%).

#define ROW_N 4096
#define TPB   256
#define C4    4   // float4 chunks per thread: 16 elements/lane

typedef float f4 __attribute__((ext_vector_type(4)));

__device__ __forceinline__ float wave_sum(float v) {
#pragma unroll
    for (int off = 32; off > 0; off >>= 1)
        v += __shfl_xor(v, off, 64);
    return v;
}

__device__ __forceinline__ float wave_max(float v) {
#pragma unroll
    for (int off = 32; off > 0; off >>= 1)
        v = fmaxf(v, __shfl_xor(v, off, 64));
    return v;
}

__global__ __launch_bounds__(TPB, 4) void subset_topk_kernel(
    const float* __restrict__ scores,
    const float* __restrict__ gnoise,
    float* __restrict__ out)
{
    constexpr float EPS = 1.17549435e-38f;  // np.finfo(float32).tiny

    // Double-buffered cross-wave reduction slots. Phase ph writes buffer
    // ph&1; reads of buffer B in phase ph complete before the barrier of
    // phase ph+1, which precedes the next write to B (phase ph+2). So one
    // barrier per phase suffices. Max-phase = ph 0, round k = ph k+1.
    __shared__ float red[2][4] __attribute__((aligned(16)));

    const int tid  = threadIdx.x;
    const int wave = tid >> 6;
    const int lane = tid & 63;

    const size_t base = (size_t)blockIdx.x * ROW_N;
    const f4* s4 = (const f4*)(scores + base);
    const f4* g4 = (const f4*)(gnoise + base);
    f4*       o4 = (f4*)(out + base);

    // ---- load s0 = scores + g (coalesced float4), track running max ----
    f4 e[C4];
    f4 vmax;
#pragma unroll
    for (int j = 0; j < C4; ++j) {
        f4 a = s4[j * TPB + tid];
        f4 b = g4[j * TPB + tid];
        e[j] = a + b;
        vmax = (j == 0) ? e[j] : __builtin_elementwise_max(vmax, e[j]);
    }
    float m = fmaxf(fmaxf(vmax.x, vmax.y), fmaxf(vmax.z, vmax.w));
    m = wave_max(m);
    if (lane == 0) red[0][wave] = m;       // phase 0 -> buffer 0
    __syncthreads();
    {
        f4 r = *(const f4*)&red[0][0];     // broadcast ds_read_b128
        m = fmaxf(fmaxf(r.x, r.y), fmaxf(r.z, r.w));
    }

    // ---- e = exp(s0 - m), kh = 0, per-lane partial sum ----
    f4 kh[C4];
    f4 acc = {0.f, 0.f, 0.f, 0.f};
#pragma unroll
    for (int j = 0; j < C4; ++j) {
        f4 t = e[j] - m;
        e[j].x = __expf(t.x);
        e[j].y = __expf(t.y);
        e[j].z = __expf(t.z);
        e[j].w = __expf(t.w);
        kh[j] = (f4){0.f, 0.f, 0.f, 0.f};
        acc += e[j];
    }
    float part = (acc.x + acc.y) + (acc.z + acc.w);

    const f4 eps4 = {EPS, EPS, EPS, EPS};

    // ---- 16 rounds: cross-wave sum -> p -> accumulate -> mask ----
#pragma unroll
    for (int k = 0; k < 16; ++k) {
        float ws = wave_sum(part);
        const int buf = (k + 1) & 1;       // phase k+1 -> buffer (k+1)&1
        if (lane == 0) red[buf][wave] = ws;
        __syncthreads();
        f4 r = *(const f4*)&red[buf][0];
        float S = (r.x + r.y) + (r.z + r.w);
        const float invS = __builtin_amdgcn_rcpf(S);

        f4 nacc = {0.f, 0.f, 0.f, 0.f};
#pragma unroll
        for (int j = 0; j < C4; ++j) {
            f4 t = e[j] * invS;            // p
            kh[j] += t;
            f4 q = __builtin_elementwise_max(1.0f - t, eps4);
            e[j] *= q;
            nacc += e[j];                  // fused: next round's sum
        }
        part = (nacc.x + nacc.y) + (nacc.z + nacc.w);
    }

    // ---- store khot (coalesced float4) ----
#pragma unroll
    for (int j = 0; j < C4; ++j)
        o4[j * TPB + tid] = kh[j];
}

extern "C" void kernel_launch(void* const* d_in, const int* in_sizes, int n_in,
                              void* d_out, int out_size, void* d_ws, size_t ws_size,
                              hipStream_t stream) {
    const float* scores = (const float*)d_in[0];
    const float* gnoise = (const float*)d_in[1];
    float* out = (float*)d_out;

    const int rows = in_sizes[0] / ROW_N;   // 8192 rows, one block each
    subset_topk_kernel<<<rows, TPB, 0, stream>>>(scores, gnoise, out);
}

// Round 3
// 321.759 us; speedup vs baseline: 5.4861x; 3.3388x over previous
//
#include <hip/hip_runtime.h>
#include <math.h>

// SubsetOperator: relaxed top-K (K=16) Gumbel-softmax, rows of N=4096.
// Exp-domain recurrence (verified): e *= max(1-p, EPS) replaces
// s += log(max(1-p,EPS)); softmax(s).
//
// R5: R4 structure (one 256-thread block / row, 16 elems/lane, double-
// buffered 4-float LDS reduce, ONE barrier per round) with the
// min-waves launch bound REMOVED. Evidence from R3/R4: any min-waves
// hint (8 or 4) drove the allocator to a 64-VGPR/8-waves-per-EU target
// and spilled e[]/kh[] to scratch -> 10-16x HBM traffic (3.8-5.9 GB vs
// 0.36 GB ideal), VALUBusy 4-8%. R0 proved the backend handles 4x this
// state spill-free when unconstrained. Natural pressure here is ~60-90
// regs -> 5-8 waves/SIMD organically.

#define ROW_N 4096
#define TPB   256
#define C4    4   // float4 chunks per thread: 16 elements/lane

typedef float f4 __attribute__((ext_vector_type(4)));

__device__ __forceinline__ float wave_sum(float v) {
#pragma unroll
    for (int off = 32; off > 0; off >>= 1)
        v += __shfl_xor(v, off, 64);
    return v;
}

__device__ __forceinline__ float wave_max(float v) {
#pragma unroll
    for (int off = 32; off > 0; off >>= 1)
        v = fmaxf(v, __shfl_xor(v, off, 64));
    return v;
}

__global__ __launch_bounds__(TPB) void subset_topk_kernel(
    const float* __restrict__ scores,
    const float* __restrict__ gnoise,
    float* __restrict__ out)
{
    constexpr float EPS = 1.17549435e-38f;  // np.finfo(float32).tiny

    // Double-buffered cross-wave reduction slots. Phase ph writes buffer
    // ph&1; reads of buffer B in phase ph complete before the barrier of
    // phase ph+1, which precedes the next write to B (phase ph+2). So one
    // barrier per phase suffices. Max-phase = ph 0, round k = ph k+1.
    __shared__ float red[2][4] __attribute__((aligned(16)));

    const int tid  = threadIdx.x;
    const int wave = tid >> 6;
    const int lane = tid & 63;

    const size_t base = (size_t)blockIdx.x * ROW_N;
    const f4* s4 = (const f4*)(scores + base);
    const f4* g4 = (const f4*)(gnoise + base);
    f4*       o4 = (f4*)(out + base);

    // ---- load s0 = scores + g (coalesced float4), track running max ----
    f4 e[C4];
    f4 vmax;
#pragma unroll
    for (int j = 0; j < C4; ++j) {
        f4 a = s4[j * TPB + tid];
        f4 b = g4[j * TPB + tid];
        e[j] = a + b;
        vmax = (j == 0) ? e[j] : __builtin_elementwise_max(vmax, e[j]);
    }
    float m = fmaxf(fmaxf(vmax.x, vmax.y), fmaxf(vmax.z, vmax.w));
    m = wave_max(m);
    if (lane == 0) red[0][wave] = m;       // phase 0 -> buffer 0
    __syncthreads();
    {
        f4 r = *(const f4*)&red[0][0];     // broadcast ds_read_b128
        m = fmaxf(fmaxf(r.x, r.y), fmaxf(r.z, r.w));
    }

    // ---- e = exp(s0 - m), kh = 0, per-lane partial sum ----
    f4 kh[C4];
    f4 acc = {0.f, 0.f, 0.f, 0.f};
#pragma unroll
    for (int j = 0; j < C4; ++j) {
        f4 t = e[j] - m;
        e[j].x = __expf(t.x);
        e[j].y = __expf(t.y);
        e[j].z = __expf(t.z);
        e[j].w = __expf(t.w);
        kh[j] = (f4){0.f, 0.f, 0.f, 0.f};
        acc += e[j];
    }
    float part = (acc.x + acc.y) + (acc.z + acc.w);

    const f4 eps4 = {EPS, EPS, EPS, EPS};

    // ---- 16 rounds: cross-wave sum -> p -> accumulate -> mask ----
    for (int k = 0; k < 16; ++k) {
        float ws = wave_sum(part);
        const int buf = (k + 1) & 1;       // phase k+1 -> buffer (k+1)&1
        if (lane == 0) red[buf][wave] = ws;
        __syncthreads();
        f4 r = *(const f4*)&red[buf][0];
        float S = (r.x + r.y) + (r.z + r.w);
        const float invS = __builtin_amdgcn_rcpf(S);

        f4 nacc = {0.f, 0.f, 0.f, 0.f};
#pragma unroll
        for (int j = 0; j < C4; ++j) {
            f4 t = e[j] * invS;            // p
            kh[j] += t;
            f4 q = __builtin_elementwise_max(1.0f - t, eps4);
            e[j] *= q;
            nacc += e[j];                  // fused: next round's sum
        }
        part = (nacc.x + nacc.y) + (nacc.z + nacc.w);
    }

    // ---- store khot (coalesced float4) ----
#pragma unroll
    for (int j = 0; j < C4; ++j)
        o4[j * TPB + tid] = kh[j];
}

extern "C" void kernel_launch(void* const* d_in, const int* in_sizes, int n_in,
                              void* d_out, int out_size, void* d_ws, size_t ws_size,
                              hipStream_t stream) {
    const float* scores = (const float*)d_in[0];
    const float* gnoise = (const float*)d_in[1];
    float* out = (float*)d_out;

    const int rows = in_sizes[0] / ROW_N;   // 8192 rows, one block each
    subset_topk_kernel<<<rows, TPB, 0, stream>>>(scores, gnoise, out);
}

// Round 5
// 314.312 us; speedup vs baseline: 5.6161x; 1.0237x over previous
//
#include <hip/hip_runtime.h>
#include <math.h>

// SubsetOperator: relaxed top-K (K=16) Gumbel-softmax, rows of N=4096.
// Exp-domain recurrence (verified): e *= max(1-p, EPS) replaces
// s += log(max(1-p,EPS)); softmax(s).
//
// R7 = R6 with the DPP builtin call fixed: __builtin_amdgcn_update_dpp
// requires constant-integer ctrl/mask args -> template parameters.
// Structure: one 256-thread block / row, 16 elems/lane, double-buffered
// 4-float LDS reduce, ONE barrier per round, NO min-waves bound (R3/R4:
// any min-waves hint forces spill -> 10-16x HBM traffic).
//  1) per-round wave_sum via gfx9 DPP (4x row_shr add + row_bcast15 +
//     row_bcast31, all VALU ~4cy) instead of 6x ds_bpermute (~40cy DS,
//     serial). Wave total lands in lane 63 -> lane 63 writes LDS slot.
//  2) inner loop FMA form: kh=fma(e,invS,kh), q=fma(e,-invS,1), max,
//     mul, add -> 5 ops/elem/round, vectorized <4 x float>.
//  3) k-loop unrolled x2 so LDS buffer parity is compile-time.

#define ROW_N 4096
#define TPB   256
#define C4    4   // float4 chunks per thread: 16 elements/lane

typedef float f4 __attribute__((ext_vector_type(4)));

template <int CTRL, int ROW_MASK>
__device__ __forceinline__ float dpp_add(float v) {
    int x = __builtin_amdgcn_update_dpp(0, __float_as_int(v),
                                        CTRL, ROW_MASK, 0xf, true);
    return v + __int_as_float(x);
}

// Full wave64 sum; result valid in lane 63 ONLY (others hold partials).
__device__ __forceinline__ float wave_sum63(float v) {
    v = dpp_add<0x111, 0xf>(v);  // row_shr:1
    v = dpp_add<0x112, 0xf>(v);  // row_shr:2
    v = dpp_add<0x114, 0xf>(v);  // row_shr:4
    v = dpp_add<0x118, 0xf>(v);  // row_shr:8  -> lane15 of each row = row sum
    v = dpp_add<0x142, 0xa>(v);  // row_bcast15 -> rows 1,3
    v = dpp_add<0x143, 0xc>(v);  // row_bcast31 -> lane 63 = full sum
    return v;
}

__device__ __forceinline__ float wave_max(float v) {
#pragma unroll
    for (int off = 32; off > 0; off >>= 1)
        v = fmaxf(v, __shfl_xor(v, off, 64));
    return v;
}

__global__ __launch_bounds__(TPB) void subset_topk_kernel(
    const float* __restrict__ scores,
    const float* __restrict__ gnoise,
    float* __restrict__ out)
{
    constexpr float EPS = 1.17549435e-38f;  // np.finfo(float32).tiny

    // Double-buffered cross-wave reduction slots. Phase ph writes buffer
    // ph&1; reads of buffer B in phase ph complete before the barrier of
    // phase ph+1, which precedes the next write to B (phase ph+2). So one
    // barrier per phase suffices. Max-phase = ph 0, round k = ph k+1.
    __shared__ float red[2][4] __attribute__((aligned(16)));

    const int tid  = threadIdx.x;
    const int wave = tid >> 6;
    const int lane = tid & 63;

    const size_t base = (size_t)blockIdx.x * ROW_N;
    const f4* s4 = (const f4*)(scores + base);
    const f4* g4 = (const f4*)(gnoise + base);
    f4*       o4 = (f4*)(out + base);

    // ---- load s0 = scores + g (coalesced float4), track running max ----
    f4 e[C4];
    f4 vmax;
#pragma unroll
    for (int j = 0; j < C4; ++j) {
        f4 a = s4[j * TPB + tid];
        f4 b = g4[j * TPB + tid];
        e[j] = a + b;
        vmax = (j == 0) ? e[j] : __builtin_elementwise_max(vmax, e[j]);
    }
    float m = fmaxf(fmaxf(vmax.x, vmax.y), fmaxf(vmax.z, vmax.w));
    m = wave_max(m);
    if (lane == 0) red[0][wave] = m;       // phase 0 -> buffer 0
    __syncthreads();
    {
        f4 r = *(const f4*)&red[0][0];     // broadcast ds_read_b128
        m = fmaxf(fmaxf(r.x, r.y), fmaxf(r.z, r.w));
    }

    // ---- e = exp(s0 - m), kh = 0, per-lane partial sum ----
    f4 kh[C4];
    f4 acc = {0.f, 0.f, 0.f, 0.f};
#pragma unroll
    for (int j = 0; j < C4; ++j) {
        f4 t = e[j] - m;
        e[j].x = __expf(t.x);
        e[j].y = __expf(t.y);
        e[j].z = __expf(t.z);
        e[j].w = __expf(t.w);
        kh[j] = (f4){0.f, 0.f, 0.f, 0.f};
        acc += e[j];
    }
    float part = (acc.x + acc.y) + (acc.z + acc.w);

    const f4 eps4 = {EPS, EPS, EPS, EPS};
    const f4 one4 = {1.f, 1.f, 1.f, 1.f};

    // ---- 16 rounds: cross-wave sum -> p -> accumulate -> mask ----
#pragma unroll 2
    for (int k = 0; k < 16; ++k) {
        float ws = wave_sum63(part);
        const int buf = (k + 1) & 1;       // phase k+1 -> buffer (k+1)&1
        if (lane == 63) red[buf][wave] = ws;
        __syncthreads();
        f4 r = *(const f4*)&red[buf][0];
        float S = (r.x + r.y) + (r.z + r.w);
        const float invS = __builtin_amdgcn_rcpf(S);
        const f4 invS4  = {invS, invS, invS, invS};
        const f4 ninvS4 = {-invS, -invS, -invS, -invS};

        f4 nacc = {0.f, 0.f, 0.f, 0.f};
#pragma unroll
        for (int j = 0; j < C4; ++j) {
            kh[j] = __builtin_elementwise_fma(e[j], invS4, kh[j]);   // kh += p
            f4 q  = __builtin_elementwise_fma(e[j], ninvS4, one4);   // 1 - p
            q     = __builtin_elementwise_max(q, eps4);
            e[j] *= q;
            nacc += e[j];                  // fused: next round's sum
        }
        part = (nacc.x + nacc.y) + (nacc.z + nacc.w);
    }

    // ---- store khot (coalesced float4) ----
#pragma unroll
    for (int j = 0; j < C4; ++j)
        o4[j * TPB + tid] = kh[j];
}

extern "C" void kernel_launch(void* const* d_in, const int* in_sizes, int n_in,
                              void* d_out, int out_size, void* d_ws, size_t ws_size,
                              hipStream_t stream) {
    const float* scores = (const float*)d_in[0];
    const float* gnoise = (const float*)d_in[1];
    float* out = (float*)d_out;

    const int rows = in_sizes[0] / ROW_N;   // 8192 rows, one block each
    subset_topk_kernel<<<rows, TPB, 0, stream>>>(scores, gnoise, out);
}